// Round 3
// baseline (77.490 us; speedup 1.0000x reference)
//
#include <hip/hip_runtime.h>

#define NBINS 51
#define NT    32          // tiles per dimension (1024 / 32)
#define TILE  32          // rows per tile
#define DV4   32          // 128 floats = 32 float4 per row
#define NBLK  (NT * (NT + 1) / 2)   // 528
#define NCOPY 16
#define HSTR  103         // hist copy stride (odd -> banks decorrelated)
#define NH    (2 * NBINS) // 102: [0..50]=pos, [51..101]=neg
#define PSTR  128         // padded partial-hist stride (512 B, float4 aligned)

// Module globals: OUTSIDE d_ws, so the harness 256 MiB re-poison fill never
// touches them. g_counter self-resets (last block zeroes it), so no memset
// node is needed -> the graph is just [harness fill] + [this kernel].
__device__ float g_part[NBLK][PSTR];
__device__ int   g_counter = 0;

// ---------------------------------------------------------------------------
// Fused kernel: pairwise dots (upper triangle) + soft histogram + last-block
// finalize. 528 blocks x 256 threads, 2x2 micro-tile per thread.
// LDS hist atomics are unsafeAtomicAdd -> native ds_add_f32 (default
// atomicAdd(float*) is a CAS loop on gfx950, serializes on hot bins).
// Completion protocol (cross-XCD safe):
//   producers: stores -> __syncthreads (vmcnt drained into L2)
//              -> t0: __threadfence (agent release: buffer_wbl2, L2->L3)
//              -> t0: atomicAdd(counter)  [device-scope, at L3]
//   last block: __threadfence (agent acquire: buffer_inv, L1+L2 invalidated)
//              -> plain float4 loads hit fresh L3 data.
// ---------------------------------------------------------------------------
__global__ __launch_bounds__(256) void fused_pair_hist_kernel(
    const float* __restrict__ x,
    const int*   __restrict__ labels,
    float*       __restrict__ out)
{
    __shared__ float4 As[TILE][DV4];   // chunk c stored at c ^ ((row>>1)&7)
    __shared__ float4 Bs[TILE][DV4];
    __shared__ int    la[TILE], lb[TILE];
    __shared__ float  shist[NCOPY * HSTR];
    __shared__ int    s_last;

    // Decode upper-triangular tile pair (bi <= bj).
    int rem = blockIdx.x;
    int bi = 0;
    while (rem >= NT - bi) { rem -= NT - bi; ++bi; }
    const int bj = bi + rem;

    const int t = threadIdx.x;
    for (int k = t; k < NCOPY * HSTR; k += 256) shist[k] = 0.0f;

    const float4* xv = (const float4*)x;
    #pragma unroll
    for (int k = 0; k < 4; ++k) {
        int e = t + 256 * k;
        int r = e >> 5;
        int c = e & 31;
        int sw = c ^ ((r >> 1) & 7);
        As[r][sw] = xv[(bi * TILE + r) * DV4 + c];
        Bs[r][sw] = xv[(bj * TILE + r) * DV4 + c];
    }
    if (t < TILE) {
        la[t] = labels[bi * TILE + t];
        lb[t] = labels[bj * TILE + t];
    }
    __syncthreads();

    const int tx = t & 15;
    const int ty = t >> 4;
    const int i0 = ty * 2, j0 = tx * 2;
    const int kA = ty & 7;
    const int kB = tx & 7;

    float acc00 = 0.f, acc01 = 0.f, acc10 = 0.f, acc11 = 0.f;
    #pragma unroll 4
    for (int d4 = 0; d4 < DV4; ++d4) {
        float4 a0 = As[i0    ][d4 ^ kA];
        float4 a1 = As[i0 + 1][d4 ^ kA];
        float4 b0 = Bs[j0    ][d4 ^ kB];
        float4 b1 = Bs[j0 + 1][d4 ^ kB];
        acc00 += a0.x*b0.x + a0.y*b0.y + a0.z*b0.z + a0.w*b0.w;
        acc01 += a0.x*b1.x + a0.y*b1.y + a0.z*b1.z + a0.w*b1.w;
        acc10 += a1.x*b0.x + a1.y*b0.y + a1.z*b0.z + a1.w*b0.w;
        acc11 += a1.x*b1.x + a1.y*b1.y + a1.z*b1.z + a1.w*b1.w;
    }

    const float BW = 2.0f / (NBINS - 1);
    float accs[2][2] = {{acc00, acc01}, {acc10, acc11}};
    float* myh = &shist[(t & (NCOPY - 1)) * HSTR];

    #pragma unroll
    for (int r = 0; r < 2; ++r) {
        #pragma unroll
        for (int c = 0; c < 2; ++c) {
            int gi = bi * TILE + i0 + r;
            int gj = bj * TILE + j0 + c;
            if (gi < gj) {
                float s = accs[r][c];
                int b = (int)floorf((s + 1.0f) / BW);
                b = min(max(b, 0), NBINS - 1);
                float v = (float)b * BW - 1.0f;
                float wlo = (v + BW - s) / BW;
                float whi = (s - v) / BW;
                int bh = min(b + 1, NBINS - 1);
                int base = (la[i0 + r] == lb[j0 + c]) ? 0 : NBINS;
                unsafeAtomicAdd(&myh[base + b],  wlo);   // native ds_add_f32
                unsafeAtomicAdd(&myh[base + bh], whi);
            }
        }
    }

    __syncthreads();
    // Reduce 16 copies; plain coalesced 512 B store to this block's slice.
    if (t < PSTR) {
        float s = 0.f;
        if (t < NH) {
            #pragma unroll
            for (int c = 0; c < NCOPY; ++c) s += shist[c * HSTR + t];
        }
        g_part[blockIdx.x][t] = s;   // pad lanes store 0
    }
    __syncthreads();   // compiler drains vmcnt(0) before s_barrier -> stores in L2

    if (t == 0) {
        __threadfence();                                   // release: L2 -> L3
        s_last = (atomicAdd(&g_counter, 1) == NBLK - 1);
    }
    __syncthreads();
    if (!s_last) return;

    // ---- last block: finalize (runs once, no extra kernel launch) ----
    __threadfence();                                       // acquire: inv L1/L2

    // Reuse As/Bs LDS for the reduction scratch.
    float (*red)[PSTR] = (float (*)[PSTR])As;   // [8][128]
    float* tot = (float*)Bs;                    // [128]

    const int c4 = t & 31;          // float4 column 0..31
    const int p  = t >> 5;          // row group 0..7
    const float4* g4 = (const float4*)&g_part[0][0];   // row stride 32 float4

    float4 acc = make_float4(0.f, 0.f, 0.f, 0.f);
    #pragma unroll 11
    for (int r = p; r < NBLK; r += 8) {                // 66 independent loads
        float4 v = g4[r * 32 + c4];
        acc.x += v.x; acc.y += v.y; acc.z += v.z; acc.w += v.w;
    }
    *(float4*)&red[p][c4 * 4] = acc;
    __syncthreads();

    if (t < PSTR) {
        float s = 0.f;
        #pragma unroll
        for (int q = 0; q < 8; ++q) s += red[q][t];
        tot[t] = s;
    }
    __syncthreads();

    if (t < 64) {
        float hp = (t < NBINS) ? tot[t]         : 0.0f;
        float hn = (t < NBINS) ? tot[NBINS + t] : 0.0f;

        float sp = hp, sn = hn;
        #pragma unroll
        for (int off = 32; off > 0; off >>= 1) {
            sp += __shfl_xor(sp, off, 64);
            sn += __shfl_xor(sn, off, 64);
        }

        float cdf = hp;
        #pragma unroll
        for (int off = 1; off < 64; off <<= 1) {
            float v = __shfl_up(cdf, off, 64);
            if (t >= off) cdf += v;
        }

        float contrib = hn * cdf;
        #pragma unroll
        for (int off = 32; off > 0; off >>= 1)
            contrib += __shfl_xor(contrib, off, 64);

        if (t == 0) out[0] = contrib / (sp * sn);
    }

    if (t == 0) g_counter = 0;   // self-reset for the next iteration
                                 // (kernel-end implicit release makes it visible)
}

extern "C" void kernel_launch(void* const* d_in, const int* in_sizes, int n_in,
                              void* d_out, int out_size, void* d_ws, size_t ws_size,
                              hipStream_t stream)
{
    const float* x      = (const float*)d_in[0];
    const int*   labels = (const int*)d_in[1];

    fused_pair_hist_kernel<<<NBLK, 256, 0, stream>>>(x, labels, (float*)d_out);
}

// Round 4
// 72.376 us; speedup vs baseline: 1.0707x; 1.0707x over previous
//
#include <hip/hip_runtime.h>

#define NBINS 51
#define NT    32          // tiles per dimension (1024 / 32)
#define TILE  32          // rows per tile
#define DV4   32          // 128 floats = 32 float4 per row
#define NBLK  (NT * (NT + 1) / 2)   // 528
#define NCOPY 16
#define HSTR  103         // hist copy stride (odd -> banks decorrelated)
#define NH    (2 * NBINS) // 102: [0..50]=pos, [51..101]=neg
#define PSTR  128         // padded partial-hist stride (512 B, float4 aligned)

typedef float v4 __attribute__((ext_vector_type(4)));
typedef float v2 __attribute__((ext_vector_type(2)));

// ---------------------------------------------------------------------------
// Kernel 1: pairwise dots (upper triangle) + soft histogram.
// 528 blocks x 256 threads, 2x2 micro-tile per thread.
// Inner loop is VALU-bound (A-reads are 16-lane broadcasts, B-swizzle holds
// LDS conflicts at 2-way = free), so accumulate in float2 ext-vectors:
// fp-contract fuses each `acc += a.xy*b.xy` into one v_pk_fma_f32 (2 FMA/
// instr, full rate on gfx950) -> FMA instruction count halves (16 -> 8/iter).
// Horizontal add hoisted out of the loop. LDS hist atomics are
// unsafeAtomicAdd -> native ds_add_f32 (default atomicAdd(float*) is a CAS
// loop on gfx950, serializes on hot bins). Epilogue: per-block partial hist
// (padded to 128 floats) written to a PRIVATE workspace slice with plain
// stores -- no zero-init needed, no cross-block atomic contention.
// ---------------------------------------------------------------------------
__global__ __launch_bounds__(256) void pair_hist_kernel(
    const float* __restrict__ x,
    const int*   __restrict__ labels,
    float*       __restrict__ gpart)   // [NBLK][PSTR]
{
    __shared__ v4  As[TILE][DV4];   // chunk c stored at c ^ ((row>>1)&7)
    __shared__ v4  Bs[TILE][DV4];
    __shared__ int la[TILE], lb[TILE];
    __shared__ float shist[NCOPY * HSTR];

    // Decode upper-triangular tile pair (bi <= bj).
    int rem = blockIdx.x;
    int bi = 0;
    while (rem >= NT - bi) { rem -= NT - bi; ++bi; }
    const int bj = bi + rem;

    const int t = threadIdx.x;
    for (int k = t; k < NCOPY * HSTR; k += 256) shist[k] = 0.0f;

    const v4* xv = (const v4*)x;
    #pragma unroll
    for (int k = 0; k < 4; ++k) {
        int e = t + 256 * k;
        int r = e >> 5;
        int c = e & 31;
        int sw = c ^ ((r >> 1) & 7);
        As[r][sw] = xv[(bi * TILE + r) * DV4 + c];
        Bs[r][sw] = xv[(bj * TILE + r) * DV4 + c];
    }
    if (t < TILE) {
        la[t] = labels[bi * TILE + t];
        lb[t] = labels[bj * TILE + t];
    }
    __syncthreads();

    const int tx = t & 15;
    const int ty = t >> 4;
    const int i0 = ty * 2, j0 = tx * 2;
    const int kA = ty & 7;
    const int kB = tx & 7;

    v2 p00 = {0.f, 0.f}, p01 = {0.f, 0.f};
    v2 p10 = {0.f, 0.f}, p11 = {0.f, 0.f};
    #pragma unroll 8
    for (int d4 = 0; d4 < DV4; ++d4) {
        v4 a0 = As[i0    ][d4 ^ kA];
        v4 a1 = As[i0 + 1][d4 ^ kA];
        v4 b0 = Bs[j0    ][d4 ^ kB];
        v4 b1 = Bs[j0 + 1][d4 ^ kB];
        p00 += a0.xy * b0.xy;  p00 += a0.zw * b0.zw;   // v_pk_fma_f32 x2
        p01 += a0.xy * b1.xy;  p01 += a0.zw * b1.zw;
        p10 += a1.xy * b0.xy;  p10 += a1.zw * b0.zw;
        p11 += a1.xy * b1.xy;  p11 += a1.zw * b1.zw;
    }
    const float acc00 = p00.x + p00.y;
    const float acc01 = p01.x + p01.y;
    const float acc10 = p10.x + p10.y;
    const float acc11 = p11.x + p11.y;

    const float BW = 2.0f / (NBINS - 1);
    float accs[2][2] = {{acc00, acc01}, {acc10, acc11}};
    float* myh = &shist[(t & (NCOPY - 1)) * HSTR];

    #pragma unroll
    for (int r = 0; r < 2; ++r) {
        #pragma unroll
        for (int c = 0; c < 2; ++c) {
            int gi = bi * TILE + i0 + r;
            int gj = bj * TILE + j0 + c;
            if (gi < gj) {
                float s = accs[r][c];
                int b = (int)floorf((s + 1.0f) / BW);
                b = min(max(b, 0), NBINS - 1);
                float v = (float)b * BW - 1.0f;
                float wlo = (v + BW - s) / BW;
                float whi = (s - v) / BW;
                int bh = min(b + 1, NBINS - 1);
                int base = (la[i0 + r] == lb[j0 + c]) ? 0 : NBINS;
                unsafeAtomicAdd(&myh[base + b],  wlo);   // native ds_add_f32
                unsafeAtomicAdd(&myh[base + bh], whi);
            }
        }
    }

    __syncthreads();
    // Reduce 16 copies; plain coalesced 512 B store to this block's slice.
    if (t < PSTR) {
        float s = 0.f;
        if (t < NH) {
            #pragma unroll
            for (int c = 0; c < NCOPY; ++c) s += shist[c * HSTR + t];
        }
        gpart[blockIdx.x * PSTR + t] = s;   // pad lanes store 0
    }
}

// ---------------------------------------------------------------------------
// Kernel 2: one block, 1024 threads. Each thread owns one float4 column of
// the [528][32] float4 partial matrix and sums 16-17 fully-unrolled
// INDEPENDENT loads (~256 KB in flight -> the whole read is one latency
// window). Then a 32-way LDS reduction, then one wave does sums, CDF scan,
// and the loss. sum(hist) over bins == pair count, so normalizers are free.
// ---------------------------------------------------------------------------
__global__ __launch_bounds__(1024) void finalize_kernel(
    const float* __restrict__ gpart,
    float*       __restrict__ out)
{
    __shared__ float red[32][PSTR];
    __shared__ float tot[PSTR];

    const int t = threadIdx.x;
    const int p = t >> 5;          // block-group 0..31
    const int c = t & 31;          // float4 column 0..31

    const float4* g4 = (const float4*)gpart;   // row stride = 32 float4

    float4 acc = make_float4(0.f, 0.f, 0.f, 0.f);
    #pragma unroll
    for (int k = 0; k < 16; ++k) {             // blocks p, p+32, ..., p+480
        float4 v = g4[(p + (k << 5)) * 32 + c];
        acc.x += v.x; acc.y += v.y; acc.z += v.z; acc.w += v.w;
    }
    if (p < 16) {                              // tail blocks 512..527
        float4 v = g4[(p + 512) * 32 + c];
        acc.x += v.x; acc.y += v.y; acc.z += v.z; acc.w += v.w;
    }
    *(float4*)&red[p][c * 4] = acc;
    __syncthreads();

    if (t < PSTR) {
        float s = 0.f;
        #pragma unroll
        for (int q = 0; q < 32; ++q) s += red[q][t];
        tot[t] = s;
    }
    __syncthreads();

    if (t < 64) {
        float hp = (t < NBINS) ? tot[t]         : 0.0f;
        float hn = (t < NBINS) ? tot[NBINS + t] : 0.0f;

        float sp = hp, sn = hn;
        #pragma unroll
        for (int off = 32; off > 0; off >>= 1) {
            sp += __shfl_xor(sp, off, 64);
            sn += __shfl_xor(sn, off, 64);
        }

        float cdf = hp;
        #pragma unroll
        for (int off = 1; off < 64; off <<= 1) {
            float v = __shfl_up(cdf, off, 64);
            if (t >= off) cdf += v;
        }

        float contrib = hn * cdf;
        #pragma unroll
        for (int off = 32; off > 0; off >>= 1)
            contrib += __shfl_xor(contrib, off, 64);

        if (t == 0) out[0] = contrib / (sp * sn);
    }
}

extern "C" void kernel_launch(void* const* d_in, const int* in_sizes, int n_in,
                              void* d_out, int out_size, void* d_ws, size_t ws_size,
                              hipStream_t stream)
{
    const float* x      = (const float*)d_in[0];
    const int*   labels = (const int*)d_in[1];
    float*       gpart  = (float*)d_ws;     // [NBLK][PSTR] partial hists

    pair_hist_kernel<<<NBLK, 256, 0, stream>>>(x, labels, gpart);
    finalize_kernel<<<1, 1024, 0, stream>>>(gpart, (float*)d_out);
}